// Round 12
// baseline (190.310 us; speedup 1.0000x reference)
//
#include <hip/hip_runtime.h>
#include <hip/hip_bf16.h>
#include <math.h>

#define B_ 4
#define CIN 64
#define H_ 160
#define W_ 160
#define COUT 64
#define KK_ 9
#define HW_ (H_ * W_)
#define KTOT 576      // 9 taps * 64 channels
#define CP32 200      // sAc pitch (u16): 400 B, 100 dw == 4 mod 32 banks
#define XPITCH 72     // strip pitch (u16): 144 B, bank-rotating
#define SL32 33       // slog pitch (floats): 33 dw == 1 mod 32, rotating
#define NT32 3200     // (B*HW)/32
#define TPX32 400     // tiles per XCD slice (NT32/8)

typedef __attribute__((ext_vector_type(8))) short bf16x8;
typedef __attribute__((ext_vector_type(4))) float f32x4;

__device__ inline unsigned short f2bf(float f) {
    unsigned int u = __float_as_uint(f);
    u = (u + 0x7FFF + ((u >> 16) & 1)) >> 16;   // round-to-nearest-even
    return (unsigned short)u;
}

// HW bf16 convert (RNE, bit-identical to f2bf on finite inputs), 1 VALU op
__device__ inline unsigned short bfc(float f) {
    __hip_bfloat16 h = __float2bfloat16(f);
    union { __hip_bfloat16 h; unsigned short u; } cv;
    cv.h = h;
    return cv.u;
}

// ---------------------------------------------------------------------------
// Kernel 1 (merged prep): unchanged (verified).
// ---------------------------------------------------------------------------
__global__ __launch_bounds__(256) void prep_all_k(const float* __restrict__ x,
                                                  const float* __restrict__ wgt,
                                                  const float* __restrict__ ow,
                                                  float* __restrict__ xt,
                                                  unsigned short* __restrict__ wB,
                                                  unsigned short* __restrict__ wB2) {
    __shared__ float tile[64][65];
    int bid = blockIdx.x;
    int t = threadIdx.x;

    if (bid < 1600) {
        int pbk = bid % 400, b = bid / 400;    // 400 pixel-blocks of 64 per image
        int p0 = pbk * 64;
        const float* xp = x + (size_t)b * CIN * HW_ + p0;

        int pg = (t & 15) * 4, cr = t >> 4;
#pragma unroll
        for (int i = 0; i < 4; i++) {
            int c = i * 16 + cr;
            float4 v = *(const float4*)(xp + (size_t)c * HW_ + pg);
            tile[c][pg]     = v.x;
            tile[c][pg + 1] = v.y;
            tile[c][pg + 2] = v.z;
            tile[c][pg + 3] = v.w;
        }
        __syncthreads();

        int c4 = (t & 15) * 4, pr = t >> 4;
        float* op = xt + ((size_t)b * HW_ + p0) * 64 + c4;
#pragma unroll
        for (int i = 0; i < 4; i++) {
            int p = i * 16 + pr;
            float4 v;
            v.x = tile[c4][p];
            v.y = tile[c4 + 1][p];
            v.z = tile[c4 + 2][p];
            v.w = tile[c4 + 3][p];
            *(float4*)(op + (size_t)p * 64) = v;
        }
    } else if (bid < 1744) {
        int i = (bid - 1600) * 256 + t;          // 64*576 = 36864
        int o = i / KTOT, r = i % KTOT;
        int tap = r >> 6, c = r & 63;
        wB[i] = f2bf(wgt[(o * CIN + c) * KK_ + tap]);
    } else {
        int i = (bid - 1744) * 256 + t;          // 32*576 = 18432
        int n = i / KTOT, r = i % KTOT;
        int tap = r >> 6, c = r & 63;
        wB2[i] = (n < 27) ? f2bf(ow[(n * CIN + c) * KK_ + tap]) : (unsigned short)0;
    }
}

// ---------------------------------------------------------------------------
// Kernel 2: FUSED DCNv2, 32 pixels per block as a 2x16 TILE (2 rows x 16 cols).
//  A : 4x18 halo strip (72 rows) -> sX bf16 (10.4 KB)   [was 3x34 = 102 rows]
//  B : offset GEMM, all 4 waves: h = wv>>1 (image row half), oc-tile wv&1;
//      strip row = (h + tap/3)*18 + m + tap%3
//  C': bilinear params, per-wave tasks {l*4+wv}; 288 tasks; p=task&31
//      pixel: image row ho+(p>>4), col wo0+(p&15);
//      spar_o PACKED int2 {base, dyoff<<16|dxoff}  (exact; saves 2.3 KB)
//  chunks c=0..2: D_c gather (24 tasks/wave, 12-deep batches) -> sAc;
//                 E_c 12 MFMA/wave, accumulate
//  Store: half h=0 -> row ho, h=1 -> row ho+1 (a0 + W_).
//  LDS ~23.3 KB -> 7 blocks/CU cap (residency ~75% of cap > TLP knee).
// ---------------------------------------------------------------------------
__global__ __launch_bounds__(256, 7) void fused_dcn_k(const float* __restrict__ xt,
                                                      const unsigned short* __restrict__ wB2,
                                                      const float* __restrict__ ob,
                                                      const unsigned short* __restrict__ wB,
                                                      const float* __restrict__ bias,
                                                      float* __restrict__ out) {
    __shared__ __align__(16) char ubuf[12800];             // sX (A/B) -> sAc (D/E)
    __shared__ __align__(16) char pbuf[288 * 24];          // spar_w | spar_o2, 6.9 KB
    __shared__ float slog[27 * SL32];                      // 3.6 KB
    unsigned short* sX  = (unsigned short*)ubuf;           // 72 x XPITCH (10.4 KB)
    unsigned short* sAc = (unsigned short*)ubuf;           // 32 x CP32 (12.8 KB)
    float4* spar_w = (float4*)pbuf;
    int2*   spar_o = (int2*)(pbuf + 288 * 16);

    int t = threadIdx.x;
    int lane = t & 63, wv = t >> 6;
    int bid = blockIdx.x;
    int t2 = (bid & 7) * TPX32 + (bid >> 3);   // XCD-contiguous tile index
    int b  = t2 / 800;                         // 800 2x16-tiles per image
    int ti = t2 % 800;                         // 80 row-pairs x 10 col-segs
    int ho  = (ti / 10) * 2;
    int wo0 = (ti % 10) * 16;

    const float* xb = xt + (size_t)b * HW_ * 64 + lane;

    // ---- phase A: 72-row halo strip (4 rows x 18 cols), lanes = channels ----
#pragma unroll
    for (int i = 0; i < 18; i++) {
        int r = i * 4 + wv;             // 0..71
        int ry = r / 18, rx = r % 18;
        int yy = ho - 1 + ry;
        int xx = wo0 - 1 + rx;
        float v = 0.f;
        if (yy >= 0 && yy < H_ && xx >= 0 && xx < W_)
            v = xb[(size_t)(yy * W_ + xx) * 64];
        sX[r * XPITCH + lane] = bfc(v);
    }
    __syncthreads();

    // ---- phase B: offset GEMM, all 4 waves (h = wv>>1, oc-tile wv&1) ----
    {
        int m = lane & 15, q = lane >> 4;
        int h  = wv >> 1;
        int ocl = (wv & 1) * 16 + m;
        float bv = (ocl < 27) ? ob[ocl] : 0.f;
        f32x4 acc  = {bv, bv, bv, bv};
        f32x4 acc2 = {0.f, 0.f, 0.f, 0.f};
        const unsigned short* brow = wB2 + ocl * KTOT + q * 8;
#pragma unroll
        for (int tap = 0; tap < 9; tap++) {
            int row = (h + tap / 3) * 18 + m + (tap % 3);   // strip row
            const unsigned short* sxr = sX + row * XPITCH + q * 8;
            bf16x8 af0 = *(const bf16x8*)(sxr);
            bf16x8 af1 = *(const bf16x8*)(sxr + 32);
            bf16x8 b0  = *(const bf16x8*)(brow + (2 * tap) * 32);
            bf16x8 b1  = *(const bf16x8*)(brow + (2 * tap + 1) * 32);
            acc  = __builtin_amdgcn_mfma_f32_16x16x32_bf16(af0, b0, acc,  0, 0, 0);
            acc2 = __builtin_amdgcn_mfma_f32_16x16x32_bf16(af1, b1, acc2, 0, 0, 0);
        }
#pragma unroll
        for (int r = 0; r < 4; r++) acc[r] += acc2[r];
        if (ocl < 27) {
            float* sl = slog + ocl * SL32 + h * 16 + q * 4;     // pixel p32
            if (ocl < 18) {
#pragma unroll
                for (int r = 0; r < 4; r++) sl[r] = acc[r];
            } else {
#pragma unroll
                for (int r = 0; r < 4; r++) sl[r] = 1.f / (1.f + expf(-acc[r]));
            }
        }
    }
    __syncthreads();

    // ---- phase C': bilinear params, per-wave task subset {l*4+wv} ----
    for (int l = lane; l < 72; l += 64) {
        int task = l * 4 + wv;                 // < 288
        int p = task & 31, k = task >> 5;
        int h = p >> 4, col = p & 15;
        float dyv = slog[(2 * k) * SL32 + p];
        float dxv = slog[(2 * k + 1) * SL32 + p];
        float mv  = slog[(18 + k) * SL32 + p];
        float py = dyv + (float)(k / 3) + (float)(ho + h - 1);
        float px = dxv + (float)(k % 3) + (float)(wo0 + col - 1);
        float y0f = floorf(py), x0f = floorf(px);
        float wy1 = py - y0f, wx1 = px - x0f;
        float wy0 = 1.f - wy1, wx0 = 1.f - wx1;
        int y0 = (int)y0f, x0 = (int)x0f;
        bool yv0 = (y0 >= 0) && (y0 < H_);
        bool yv1 = (y0 + 1 >= 0) && (y0 + 1 < H_);
        bool xv0 = (x0 >= 0) && (x0 < W_);
        bool xv1 = (x0 + 1 >= 0) && (x0 + 1 < W_);
        float4 w4;
        w4.x = (yv0 && xv0) ? wy0 * wx0 * mv : 0.f;
        w4.y = (yv0 && xv1) ? wy0 * wx1 * mv : 0.f;
        w4.z = (yv1 && xv0) ? wy1 * wx0 * mv : 0.f;
        w4.w = (yv1 && xv1) ? wy1 * wx1 * mv : 0.f;
        spar_w[task] = w4;
        int yc0 = min(max(y0, 0), H_ - 1), yc1 = min(max(y0 + 1, 0), H_ - 1);
        int xc0 = min(max(x0, 0), W_ - 1), xc1 = min(max(x0 + 1, 0), W_ - 1);
        int base  = (yc0 * W_ + xc0) * 256;          // BYTE offset
        int dyoff = (yc1 - yc0) * (W_ * 256);        // 0 or 40960 (fits u16)
        int dxoff = (xc1 - xc0) * 256;               // 0 or 256
        int2 o2; o2.x = base; o2.y = (dyoff << 16) | dxoff;
        spar_o[task] = o2;
    }
    // within-wave C'->D dependency: drain LDS writes, no block barrier needed
    __asm__ volatile("s_waitcnt lgkmcnt(0)" ::: "memory");

    // ---- persistent accumulators for main GEMM (2 row-halves) ----
    int m = lane & 15, q = lane >> 4;
    int o0 = wv * 16 + m;
    float b0v = bias[o0];
    f32x4 acc00 = {b0v, b0v, b0v, b0v};        // h=0, even K-slice
    f32x4 acc01 = {0.f, 0.f, 0.f, 0.f};        // h=0, odd
    f32x4 acc10 = {b0v, b0v, b0v, b0v};        // h=1, even
    f32x4 acc11 = {0.f, 0.f, 0.f, 0.f};        // h=1, odd
    const unsigned short* br0 = wB + o0 * KTOT + q * 8;
    const unsigned short* arow0 = sAc + m * CP32 + q * 8;
    const unsigned short* arow1 = sAc + (16 + m) * CP32 + q * 8;

    unsigned lane4 = (unsigned)lane << 2;
    const char* xu = (const char*)xt + (size_t)b * ((size_t)HW_ * 64 * 4);

    // ---- chunks: D_c gather (3 taps, 96 tasks) -> sAc ; E_c 12-MFMA ----
#pragma unroll
    for (int c = 0; c < 3; c++) {
        // D_c: this wave's 24 tasks, two 12-task batches
#pragma unroll
        for (int g = 0; g < 2; g++) {
            float v00[12], v01[12], v10[12], v11[12];
#pragma unroll
            for (int j = 0; j < 12; j++) {
                int task = 96 * c + (g * 12 + j) * 4 + wv;
                int2 o2 = spar_o[task];
                unsigned base = (unsigned)o2.x + lane4;
                unsigned dyo  = (unsigned)o2.y >> 16;
                unsigned dxo  = (unsigned)o2.y & 0xffffu;
                v00[j] = *(const float*)(xu + base);
                v01[j] = *(const float*)(xu + base + dxo);
                v10[j] = *(const float*)(xu + base + dyo);
                v11[j] = *(const float*)(xu + base + dyo + dxo);
            }
#pragma unroll
            for (int j = 0; j < 12; j++) {
                int task = 96 * c + (g * 12 + j) * 4 + wv;
                float4 w4 = spar_w[task];
                int p = task & 31, kc = (task >> 5) - 3 * c;   // local tap 0..2
                float v = v00[j] * w4.x + v01[j] * w4.y
                        + v10[j] * w4.z + v11[j] * w4.w;
                sAc[p * CP32 + kc * 64 + lane] = bfc(v);
            }
        }
        __syncthreads();

        // E_c: 3 local taps x 2 K-slices x 2 halves; B-frags shared
#pragma unroll
        for (int tl = 0; tl < 3; tl++) {
            bf16x8 b0  = *(const bf16x8*)(br0 + ((c * 3 + tl) * 2) * 32);
            bf16x8 b1  = *(const bf16x8*)(br0 + ((c * 3 + tl) * 2 + 1) * 32);
            bf16x8 a00 = *(const bf16x8*)(arow0 + (2 * tl) * 32);
            bf16x8 a01 = *(const bf16x8*)(arow0 + (2 * tl + 1) * 32);
            bf16x8 a10 = *(const bf16x8*)(arow1 + (2 * tl) * 32);
            bf16x8 a11 = *(const bf16x8*)(arow1 + (2 * tl + 1) * 32);
            acc00 = __builtin_amdgcn_mfma_f32_16x16x32_bf16(a00, b0, acc00, 0, 0, 0);
            acc01 = __builtin_amdgcn_mfma_f32_16x16x32_bf16(a01, b1, acc01, 0, 0, 0);
            acc10 = __builtin_amdgcn_mfma_f32_16x16x32_bf16(a10, b0, acc10, 0, 0, 0);
            acc11 = __builtin_amdgcn_mfma_f32_16x16x32_bf16(a11, b1, acc11, 0, 0, 0);
        }
        if (c < 2) __syncthreads();    // E_c reads done before D_{c+1} overwrites
    }

#pragma unroll
    for (int r = 0; r < 4; r++) { acc00[r] += acc01[r]; acc10[r] += acc11[r]; }

    // ---- direct store: half 0 -> row ho, half 1 -> row ho+1 ----
    size_t a0 = ((size_t)(b * COUT + o0)) * HW_ + (size_t)ho * W_ + wo0 + q * 4;
    float4 r0; r0.x = acc00[0]; r0.y = acc00[1]; r0.z = acc00[2]; r0.w = acc00[3];
    *(float4*)(out + a0) = r0;
    float4 r1; r1.x = acc10[0]; r1.y = acc10[1]; r1.z = acc10[2]; r1.w = acc10[3];
    *(float4*)(out + a0 + W_) = r1;
}

// ---------------------------------------------------------------------------
extern "C" void kernel_launch(void* const* d_in, const int* in_sizes, int n_in,
                              void* d_out, int out_size, void* d_ws, size_t ws_size,
                              hipStream_t stream) {
    const float* x    = (const float*)d_in[0];   // (4,64,160,160)
    const float* ow   = (const float*)d_in[1];   // (27,64,3,3)
    const float* ob   = (const float*)d_in[2];   // (27,)
    const float* wgt  = (const float*)d_in[3];   // (64,64,3,3)
    const float* bias = (const float*)d_in[4];   // (64,)
    float* out = (float*)d_out;                  // (4,64,160,160) fp32

    // workspace: xt fp32 NHWC | wB bf16 | wB2 bf16   (~26.3 MB)
    float* ws  = (float*)d_ws;
    float* xt  = ws;                                            // 6,553,600 f32
    unsigned short* wB  = (unsigned short*)(xt + (size_t)B_ * HW_ * CIN);  // 36,864 u16
    unsigned short* wB2 = wB + (size_t)COUT * KTOT;                        // 18,432 u16

    prep_all_k<<<1816, 256, 0, stream>>>(x, wgt, ow, xt, wB, wB2);
    fused_dcn_k<<<NT32, 256, 0, stream>>>(xt, wB2, ob, wB, bias, out);
}

// Round 13
// 180.486 us; speedup vs baseline: 1.0544x; 1.0544x over previous
//
#include <hip/hip_runtime.h>
#include <hip/hip_bf16.h>
#include <math.h>

#define B_ 4
#define CIN 64
#define H_ 160
#define W_ 160
#define COUT 64
#define KK_ 9
#define HW_ (H_ * W_)
#define KTOT 576      // 9 taps * 64 channels
#define CP32 200      // sAc pitch (u16): 400 B, 100 dw == 4 mod 32 banks
#define XPITCH 72     // strip pitch (u16): 144 B, bank-rotating
#define SL32 33       // slog pitch (floats): 33 dw == 1 mod 32, rotating
#define NT32 3200     // (B*HW)/32
#define TPX32 400     // tiles per XCD slice (NT32/8)

typedef __attribute__((ext_vector_type(8))) short bf16x8;
typedef __attribute__((ext_vector_type(4))) float f32x4;

__device__ inline unsigned short f2bf(float f) {
    unsigned int u = __float_as_uint(f);
    u = (u + 0x7FFF + ((u >> 16) & 1)) >> 16;   // round-to-nearest-even
    return (unsigned short)u;
}

// HW bf16 convert (RNE, bit-identical to f2bf on finite inputs), 1 VALU op
__device__ inline unsigned short bfc(float f) {
    __hip_bfloat16 h = __float2bfloat16(f);
    union { __hip_bfloat16 h; unsigned short u; } cv;
    cv.h = h;
    return cv.u;
}

// ---------------------------------------------------------------------------
// Kernel 1 (merged prep): unchanged (verified).
// ---------------------------------------------------------------------------
__global__ __launch_bounds__(256) void prep_all_k(const float* __restrict__ x,
                                                  const float* __restrict__ wgt,
                                                  const float* __restrict__ ow,
                                                  float* __restrict__ xt,
                                                  unsigned short* __restrict__ wB,
                                                  unsigned short* __restrict__ wB2) {
    __shared__ float tile[64][65];
    int bid = blockIdx.x;
    int t = threadIdx.x;

    if (bid < 1600) {
        int pbk = bid % 400, b = bid / 400;    // 400 pixel-blocks of 64 per image
        int p0 = pbk * 64;
        const float* xp = x + (size_t)b * CIN * HW_ + p0;

        int pg = (t & 15) * 4, cr = t >> 4;
#pragma unroll
        for (int i = 0; i < 4; i++) {
            int c = i * 16 + cr;
            float4 v = *(const float4*)(xp + (size_t)c * HW_ + pg);
            tile[c][pg]     = v.x;
            tile[c][pg + 1] = v.y;
            tile[c][pg + 2] = v.z;
            tile[c][pg + 3] = v.w;
        }
        __syncthreads();

        int c4 = (t & 15) * 4, pr = t >> 4;
        float* op = xt + ((size_t)b * HW_ + p0) * 64 + c4;
#pragma unroll
        for (int i = 0; i < 4; i++) {
            int p = i * 16 + pr;
            float4 v;
            v.x = tile[c4][p];
            v.y = tile[c4 + 1][p];
            v.z = tile[c4 + 2][p];
            v.w = tile[c4 + 3][p];
            *(float4*)(op + (size_t)p * 64) = v;
        }
    } else if (bid < 1744) {
        int i = (bid - 1600) * 256 + t;          // 64*576 = 36864
        int o = i / KTOT, r = i % KTOT;
        int tap = r >> 6, c = r & 63;
        wB[i] = f2bf(wgt[(o * CIN + c) * KK_ + tap]);
    } else {
        int i = (bid - 1744) * 256 + t;          // 32*576 = 18432
        int n = i / KTOT, r = i % KTOT;
        int tap = r >> 6, c = r & 63;
        wB2[i] = (n < 27) ? f2bf(ow[(n * CIN + c) * KK_ + tap]) : (unsigned short)0;
    }
}

// ---------------------------------------------------------------------------
// Kernel 2: FUSED DCNv2, 32 pixels per block as a 2x16 TILE, K-chunked.
//  Single change vs the verified R10 kernel: tile geometry 1x32 -> 2x16.
//  A : 4x18 halo strip (72 rows) -> sX bf16 (10.4 KB)  [was 102 rows]
//  B : offset GEMM, all 4 waves; strip row = (h + tap/3)*18 + m + tap%3
//  C': bilinear params; pixel = (row ho+(p>>4), col wo0+(p&15));
//      spar_o = PLAIN int4 full byte offsets (the only addressing path that
//      compiles clean -- R7/R12 variants spilled to scratch)
//  chunks c=0..2: D_c gather (24 tasks/wave, four 6-task batches) -> sAc;
//                 E_c 12 MFMA/wave, accumulate
//  Store: half h=0 -> row ho, h=1 -> row ho+1 (a0 + W_).
//  LDS 25.6 KB -> 6 blocks/CU cap.
// ---------------------------------------------------------------------------
__global__ __launch_bounds__(256, 6) void fused_dcn_k(const float* __restrict__ xt,
                                                      const unsigned short* __restrict__ wB2,
                                                      const float* __restrict__ ob,
                                                      const unsigned short* __restrict__ wB,
                                                      const float* __restrict__ bias,
                                                      float* __restrict__ out) {
    __shared__ __align__(16) char ubuf[12800];             // sX (A/B) -> sAc (D/E)
    __shared__ __align__(16) char pbuf[288 * 32];          // spar_w | spar_o, 9.2 KB
    __shared__ float slog[27 * SL32];                      // 3.6 KB
    unsigned short* sX  = (unsigned short*)ubuf;           // 72 x XPITCH (10.4 KB)
    unsigned short* sAc = (unsigned short*)ubuf;           // 32 x CP32 (12.8 KB)
    float4* spar_w = (float4*)pbuf;
    int4*   spar_o = (int4*)(pbuf + 288 * 16);

    int t = threadIdx.x;
    int lane = t & 63, wv = t >> 6;
    int bid = blockIdx.x;
    int t2 = (bid & 7) * TPX32 + (bid >> 3);   // XCD-contiguous tile index
    int b  = t2 / 800;                         // 800 2x16-tiles per image
    int ti = t2 % 800;                         // 80 row-pairs x 10 col-segs
    int ho  = (ti / 10) * 2;
    int wo0 = (ti % 10) * 16;

    const float* xb = xt + (size_t)b * HW_ * 64 + lane;

    // ---- phase A: 72-row halo strip (4 rows x 18 cols), lanes = channels ----
#pragma unroll
    for (int i = 0; i < 18; i++) {
        int r = i * 4 + wv;             // 0..71
        int ry = r / 18, rx = r % 18;
        int yy = ho - 1 + ry;
        int xx = wo0 - 1 + rx;
        float v = 0.f;
        if (yy >= 0 && yy < H_ && xx >= 0 && xx < W_)
            v = xb[(size_t)(yy * W_ + xx) * 64];
        sX[r * XPITCH + lane] = bfc(v);
    }
    __syncthreads();

    // ---- phase B: offset GEMM, all 4 waves (h = wv>>1, oc-tile wv&1) ----
    {
        int m = lane & 15, q = lane >> 4;
        int h  = wv >> 1;
        int ocl = (wv & 1) * 16 + m;
        float bv = (ocl < 27) ? ob[ocl] : 0.f;
        f32x4 acc  = {bv, bv, bv, bv};
        f32x4 acc2 = {0.f, 0.f, 0.f, 0.f};
        const unsigned short* brow = wB2 + ocl * KTOT + q * 8;
#pragma unroll
        for (int tap = 0; tap < 9; tap++) {
            int row = (h + tap / 3) * 18 + m + (tap % 3);   // strip row
            const unsigned short* sxr = sX + row * XPITCH + q * 8;
            bf16x8 af0 = *(const bf16x8*)(sxr);
            bf16x8 af1 = *(const bf16x8*)(sxr + 32);
            bf16x8 b0  = *(const bf16x8*)(brow + (2 * tap) * 32);
            bf16x8 b1  = *(const bf16x8*)(brow + (2 * tap + 1) * 32);
            acc  = __builtin_amdgcn_mfma_f32_16x16x32_bf16(af0, b0, acc,  0, 0, 0);
            acc2 = __builtin_amdgcn_mfma_f32_16x16x32_bf16(af1, b1, acc2, 0, 0, 0);
        }
#pragma unroll
        for (int r = 0; r < 4; r++) acc[r] += acc2[r];
        if (ocl < 27) {
            float* sl = slog + ocl * SL32 + h * 16 + q * 4;     // pixel p32
            if (ocl < 18) {
#pragma unroll
                for (int r = 0; r < 4; r++) sl[r] = acc[r];
            } else {
#pragma unroll
                for (int r = 0; r < 4; r++) sl[r] = 1.f / (1.f + expf(-acc[r]));
            }
        }
    }
    __syncthreads();

    // ---- phase C': bilinear params, per-wave task subset {l*4+wv} ----
    for (int l = lane; l < 72; l += 64) {
        int task = l * 4 + wv;                 // < 288
        int p = task & 31, k = task >> 5;
        int h = p >> 4, col = p & 15;
        float dyv = slog[(2 * k) * SL32 + p];
        float dxv = slog[(2 * k + 1) * SL32 + p];
        float mv  = slog[(18 + k) * SL32 + p];
        float py = dyv + (float)(k / 3) + (float)(ho + h - 1);
        float px = dxv + (float)(k % 3) + (float)(wo0 + col - 1);
        float y0f = floorf(py), x0f = floorf(px);
        float wy1 = py - y0f, wx1 = px - x0f;
        float wy0 = 1.f - wy1, wx0 = 1.f - wx1;
        int y0 = (int)y0f, x0 = (int)x0f;
        bool yv0 = (y0 >= 0) && (y0 < H_);
        bool yv1 = (y0 + 1 >= 0) && (y0 + 1 < H_);
        bool xv0 = (x0 >= 0) && (x0 < W_);
        bool xv1 = (x0 + 1 >= 0) && (x0 + 1 < W_);
        float4 w4;
        w4.x = (yv0 && xv0) ? wy0 * wx0 * mv : 0.f;
        w4.y = (yv0 && xv1) ? wy0 * wx1 * mv : 0.f;
        w4.z = (yv1 && xv0) ? wy1 * wx0 * mv : 0.f;
        w4.w = (yv1 && xv1) ? wy1 * wx1 * mv : 0.f;
        spar_w[task] = w4;
        int yc0 = min(max(y0, 0), H_ - 1), yc1 = min(max(y0 + 1, 0), H_ - 1);
        int xc0 = min(max(x0, 0), W_ - 1), xc1 = min(max(x0 + 1, 0), W_ - 1);
        int4 o4;                               // BYTE offsets (elem*64*4)
        o4.x = (yc0 * W_ + xc0) * 256;
        o4.y = (yc0 * W_ + xc1) * 256;
        o4.z = (yc1 * W_ + xc0) * 256;
        o4.w = (yc1 * W_ + xc1) * 256;
        spar_o[task] = o4;
    }
    // within-wave C'->D dependency: drain LDS writes, no block barrier needed
    __asm__ volatile("s_waitcnt lgkmcnt(0)" ::: "memory");

    // ---- persistent accumulators for main GEMM (2 row-halves) ----
    int m = lane & 15, q = lane >> 4;
    int o0 = wv * 16 + m;
    float b0v = bias[o0];
    f32x4 acc00 = {b0v, b0v, b0v, b0v};        // h=0, even K-slice
    f32x4 acc01 = {0.f, 0.f, 0.f, 0.f};        // h=0, odd
    f32x4 acc10 = {b0v, b0v, b0v, b0v};        // h=1, even
    f32x4 acc11 = {0.f, 0.f, 0.f, 0.f};        // h=1, odd
    const unsigned short* br0 = wB + o0 * KTOT + q * 8;
    const unsigned short* arow0 = sAc + m * CP32 + q * 8;
    const unsigned short* arow1 = sAc + (16 + m) * CP32 + q * 8;

    unsigned lane4 = (unsigned)lane << 2;
    const char* xu = (const char*)xt + (size_t)b * ((size_t)HW_ * 64 * 4);

    // ---- chunks: D_c gather (3 taps, 96 tasks) -> sAc ; E_c 12-MFMA ----
#pragma unroll
    for (int c = 0; c < 3; c++) {
        // D_c: this wave's 24 tasks, four 6-task batches (R10-proven pattern)
#pragma unroll
        for (int g = 0; g < 4; g++) {
            float v00[6], v01[6], v10[6], v11[6];
#pragma unroll
            for (int j = 0; j < 6; j++) {
                int task = 96 * c + (g * 6 + j) * 4 + wv;
                int4 o4 = spar_o[task];
                v00[j] = *(const float*)(xu + ((unsigned)o4.x + lane4));
                v01[j] = *(const float*)(xu + ((unsigned)o4.y + lane4));
                v10[j] = *(const float*)(xu + ((unsigned)o4.z + lane4));
                v11[j] = *(const float*)(xu + ((unsigned)o4.w + lane4));
            }
#pragma unroll
            for (int j = 0; j < 6; j++) {
                int task = 96 * c + (g * 6 + j) * 4 + wv;
                float4 w4 = spar_w[task];
                int p = task & 31, kc = (task >> 5) - 3 * c;   // local tap 0..2
                float v = v00[j] * w4.x + v01[j] * w4.y
                        + v10[j] * w4.z + v11[j] * w4.w;
                sAc[p * CP32 + kc * 64 + lane] = bfc(v);
            }
        }
        __syncthreads();

        // E_c: 3 local taps x 2 K-slices x 2 halves; B-frags shared
#pragma unroll
        for (int tl = 0; tl < 3; tl++) {
            bf16x8 b0  = *(const bf16x8*)(br0 + ((c * 3 + tl) * 2) * 32);
            bf16x8 b1  = *(const bf16x8*)(br0 + ((c * 3 + tl) * 2 + 1) * 32);
            bf16x8 a00 = *(const bf16x8*)(arow0 + (2 * tl) * 32);
            bf16x8 a01 = *(const bf16x8*)(arow0 + (2 * tl + 1) * 32);
            bf16x8 a10 = *(const bf16x8*)(arow1 + (2 * tl) * 32);
            bf16x8 a11 = *(const bf16x8*)(arow1 + (2 * tl + 1) * 32);
            acc00 = __builtin_amdgcn_mfma_f32_16x16x32_bf16(a00, b0, acc00, 0, 0, 0);
            acc01 = __builtin_amdgcn_mfma_f32_16x16x32_bf16(a01, b1, acc01, 0, 0, 0);
            acc10 = __builtin_amdgcn_mfma_f32_16x16x32_bf16(a10, b0, acc10, 0, 0, 0);
            acc11 = __builtin_amdgcn_mfma_f32_16x16x32_bf16(a11, b1, acc11, 0, 0, 0);
        }
        if (c < 2) __syncthreads();    // E_c reads done before D_{c+1} overwrites
    }

#pragma unroll
    for (int r = 0; r < 4; r++) { acc00[r] += acc01[r]; acc10[r] += acc11[r]; }

    // ---- direct store: half 0 -> row ho, half 1 -> row ho+1 ----
    size_t a0 = ((size_t)(b * COUT + o0)) * HW_ + (size_t)ho * W_ + wo0 + q * 4;
    float4 r0; r0.x = acc00[0]; r0.y = acc00[1]; r0.z = acc00[2]; r0.w = acc00[3];
    *(float4*)(out + a0) = r0;
    float4 r1; r1.x = acc10[0]; r1.y = acc10[1]; r1.z = acc10[2]; r1.w = acc10[3];
    *(float4*)(out + a0 + W_) = r1;
}

// ---------------------------------------------------------------------------
extern "C" void kernel_launch(void* const* d_in, const int* in_sizes, int n_in,
                              void* d_out, int out_size, void* d_ws, size_t ws_size,
                              hipStream_t stream) {
    const float* x    = (const float*)d_in[0];   // (4,64,160,160)
    const float* ow   = (const float*)d_in[1];   // (27,64,3,3)
    const float* ob   = (const float*)d_in[2];   // (27,)
    const float* wgt  = (const float*)d_in[3];   // (64,64,3,3)
    const float* bias = (const float*)d_in[4];   // (64,)
    float* out = (float*)d_out;                  // (4,64,160,160) fp32

    // workspace: xt fp32 NHWC | wB bf16 | wB2 bf16   (~26.3 MB)
    float* ws  = (float*)d_ws;
    float* xt  = ws;                                            // 6,553,600 f32
    unsigned short* wB  = (unsigned short*)(xt + (size_t)B_ * HW_ * CIN);  // 36,864 u16
    unsigned short* wB2 = wB + (size_t)COUT * KTOT;                        // 18,432 u16

    prep_all_k<<<1816, 256, 0, stream>>>(x, wgt, ow, xt, wB, wB2);
    fused_dcn_k<<<NT32, 256, 0, stream>>>(xt, wB2, ob, wB, bias, out);
}

// Round 14
// 179.561 us; speedup vs baseline: 1.0599x; 1.0052x over previous
//
#include <hip/hip_runtime.h>
#include <hip/hip_bf16.h>
#include <math.h>

#define B_ 4
#define CIN 64
#define H_ 160
#define W_ 160
#define COUT 64
#define KK_ 9
#define HW_ (H_ * W_)
#define KTOT 576      // 9 taps * 64 channels
#define CP32 200      // sAc pitch (u16): 400 B, 100 dw == 4 mod 32 banks
#define XPITCH 72     // strip pitch (u16): 144 B, bank-rotating
#define SL32 33       // slog pitch (floats): 33 dw == 1 mod 32, rotating
#define NT32 3200     // (B*HW)/32
#define TPX32 400     // tiles per XCD slice (NT32/8)

typedef __attribute__((ext_vector_type(8))) short bf16x8;
typedef __attribute__((ext_vector_type(4))) float f32x4;

__device__ inline unsigned short f2bf(float f) {
    unsigned int u = __float_as_uint(f);
    u = (u + 0x7FFF + ((u >> 16) & 1)) >> 16;   // round-to-nearest-even
    return (unsigned short)u;
}

// HW bf16 convert (RNE, bit-identical to f2bf on finite inputs), 1 VALU op
__device__ inline unsigned short bfc(float f) {
    __hip_bfloat16 h = __float2bfloat16(f);
    union { __hip_bfloat16 h; unsigned short u; } cv;
    cv.h = h;
    return cv.u;
}

// ---------------------------------------------------------------------------
// Kernel 1 (merged prep): unchanged (verified).
// ---------------------------------------------------------------------------
__global__ __launch_bounds__(256) void prep_all_k(const float* __restrict__ x,
                                                  const float* __restrict__ wgt,
                                                  const float* __restrict__ ow,
                                                  float* __restrict__ xt,
                                                  unsigned short* __restrict__ wB,
                                                  unsigned short* __restrict__ wB2) {
    __shared__ float tile[64][65];
    int bid = blockIdx.x;
    int t = threadIdx.x;

    if (bid < 1600) {
        int pbk = bid % 400, b = bid / 400;    // 400 pixel-blocks of 64 per image
        int p0 = pbk * 64;
        const float* xp = x + (size_t)b * CIN * HW_ + p0;

        int pg = (t & 15) * 4, cr = t >> 4;
#pragma unroll
        for (int i = 0; i < 4; i++) {
            int c = i * 16 + cr;
            float4 v = *(const float4*)(xp + (size_t)c * HW_ + pg);
            tile[c][pg]     = v.x;
            tile[c][pg + 1] = v.y;
            tile[c][pg + 2] = v.z;
            tile[c][pg + 3] = v.w;
        }
        __syncthreads();

        int c4 = (t & 15) * 4, pr = t >> 4;
        float* op = xt + ((size_t)b * HW_ + p0) * 64 + c4;
#pragma unroll
        for (int i = 0; i < 4; i++) {
            int p = i * 16 + pr;
            float4 v;
            v.x = tile[c4][p];
            v.y = tile[c4 + 1][p];
            v.z = tile[c4 + 2][p];
            v.w = tile[c4 + 3][p];
            *(float4*)(op + (size_t)p * 64) = v;
        }
    } else if (bid < 1744) {
        int i = (bid - 1600) * 256 + t;          // 64*576 = 36864
        int o = i / KTOT, r = i % KTOT;
        int tap = r >> 6, c = r & 63;
        wB[i] = f2bf(wgt[(o * CIN + c) * KK_ + tap]);
    } else {
        int i = (bid - 1744) * 256 + t;          // 32*576 = 18432
        int n = i / KTOT, r = i % KTOT;
        int tap = r >> 6, c = r & 63;
        wB2[i] = (n < 27) ? f2bf(ow[(n * CIN + c) * KK_ + tap]) : (unsigned short)0;
    }
}

// ---------------------------------------------------------------------------
// Kernel 2: FUSED DCNv2, 2x16 tile, K-chunked.  Single change vs verified R13:
//  E's wB B-fragments are preloaded into NAMED bf16x8 registers inside D_c's
//  region (issued while the 24 gather loads are in flight), consumed after the
//  barrier in E_c -- hides wB's L2 latency under the gather latency.
//  (Named scalars across one barrier = acc precedent, not the array-spill trap.)
// ---------------------------------------------------------------------------
__global__ __launch_bounds__(256, 6) void fused_dcn_k(const float* __restrict__ xt,
                                                      const unsigned short* __restrict__ wB2,
                                                      const float* __restrict__ ob,
                                                      const unsigned short* __restrict__ wB,
                                                      const float* __restrict__ bias,
                                                      float* __restrict__ out) {
    __shared__ __align__(16) char ubuf[12800];             // sX (A/B) -> sAc (D/E)
    __shared__ __align__(16) char pbuf[288 * 32];          // spar_w | spar_o, 9.2 KB
    __shared__ float slog[27 * SL32];                      // 3.6 KB
    unsigned short* sX  = (unsigned short*)ubuf;           // 72 x XPITCH (10.4 KB)
    unsigned short* sAc = (unsigned short*)ubuf;           // 32 x CP32 (12.8 KB)
    float4* spar_w = (float4*)pbuf;
    int4*   spar_o = (int4*)(pbuf + 288 * 16);

    int t = threadIdx.x;
    int lane = t & 63, wv = t >> 6;
    int bid = blockIdx.x;
    int t2 = (bid & 7) * TPX32 + (bid >> 3);   // XCD-contiguous tile index
    int b  = t2 / 800;                         // 800 2x16-tiles per image
    int ti = t2 % 800;                         // 80 row-pairs x 10 col-segs
    int ho  = (ti / 10) * 2;
    int wo0 = (ti % 10) * 16;

    const float* xb = xt + (size_t)b * HW_ * 64 + lane;

    // ---- phase A: 72-row halo strip (4 rows x 18 cols), lanes = channels ----
#pragma unroll
    for (int i = 0; i < 18; i++) {
        int r = i * 4 + wv;             // 0..71
        int ry = r / 18, rx = r % 18;
        int yy = ho - 1 + ry;
        int xx = wo0 - 1 + rx;
        float v = 0.f;
        if (yy >= 0 && yy < H_ && xx >= 0 && xx < W_)
            v = xb[(size_t)(yy * W_ + xx) * 64];
        sX[r * XPITCH + lane] = bfc(v);
    }
    __syncthreads();

    // ---- phase B: offset GEMM, all 4 waves (h = wv>>1, oc-tile wv&1) ----
    {
        int m = lane & 15, q = lane >> 4;
        int h  = wv >> 1;
        int ocl = (wv & 1) * 16 + m;
        float bv = (ocl < 27) ? ob[ocl] : 0.f;
        f32x4 acc  = {bv, bv, bv, bv};
        f32x4 acc2 = {0.f, 0.f, 0.f, 0.f};
        const unsigned short* brow = wB2 + ocl * KTOT + q * 8;
#pragma unroll
        for (int tap = 0; tap < 9; tap++) {
            int row = (h + tap / 3) * 18 + m + (tap % 3);   // strip row
            const unsigned short* sxr = sX + row * XPITCH + q * 8;
            bf16x8 af0 = *(const bf16x8*)(sxr);
            bf16x8 af1 = *(const bf16x8*)(sxr + 32);
            bf16x8 b0  = *(const bf16x8*)(brow + (2 * tap) * 32);
            bf16x8 b1  = *(const bf16x8*)(brow + (2 * tap + 1) * 32);
            acc  = __builtin_amdgcn_mfma_f32_16x16x32_bf16(af0, b0, acc,  0, 0, 0);
            acc2 = __builtin_amdgcn_mfma_f32_16x16x32_bf16(af1, b1, acc2, 0, 0, 0);
        }
#pragma unroll
        for (int r = 0; r < 4; r++) acc[r] += acc2[r];
        if (ocl < 27) {
            float* sl = slog + ocl * SL32 + h * 16 + q * 4;     // pixel p32
            if (ocl < 18) {
#pragma unroll
                for (int r = 0; r < 4; r++) sl[r] = acc[r];
            } else {
#pragma unroll
                for (int r = 0; r < 4; r++) sl[r] = 1.f / (1.f + expf(-acc[r]));
            }
        }
    }
    __syncthreads();

    // ---- phase C': bilinear params, per-wave task subset {l*4+wv} ----
    for (int l = lane; l < 72; l += 64) {
        int task = l * 4 + wv;                 // < 288
        int p = task & 31, k = task >> 5;
        int h = p >> 4, col = p & 15;
        float dyv = slog[(2 * k) * SL32 + p];
        float dxv = slog[(2 * k + 1) * SL32 + p];
        float mv  = slog[(18 + k) * SL32 + p];
        float py = dyv + (float)(k / 3) + (float)(ho + h - 1);
        float px = dxv + (float)(k % 3) + (float)(wo0 + col - 1);
        float y0f = floorf(py), x0f = floorf(px);
        float wy1 = py - y0f, wx1 = px - x0f;
        float wy0 = 1.f - wy1, wx0 = 1.f - wx1;
        int y0 = (int)y0f, x0 = (int)x0f;
        bool yv0 = (y0 >= 0) && (y0 < H_);
        bool yv1 = (y0 + 1 >= 0) && (y0 + 1 < H_);
        bool xv0 = (x0 >= 0) && (x0 < W_);
        bool xv1 = (x0 + 1 >= 0) && (x0 + 1 < W_);
        float4 w4;
        w4.x = (yv0 && xv0) ? wy0 * wx0 * mv : 0.f;
        w4.y = (yv0 && xv1) ? wy0 * wx1 * mv : 0.f;
        w4.z = (yv1 && xv0) ? wy1 * wx0 * mv : 0.f;
        w4.w = (yv1 && xv1) ? wy1 * wx1 * mv : 0.f;
        spar_w[task] = w4;
        int yc0 = min(max(y0, 0), H_ - 1), yc1 = min(max(y0 + 1, 0), H_ - 1);
        int xc0 = min(max(x0, 0), W_ - 1), xc1 = min(max(x0 + 1, 0), W_ - 1);
        int4 o4;                               // BYTE offsets (elem*64*4)
        o4.x = (yc0 * W_ + xc0) * 256;
        o4.y = (yc0 * W_ + xc1) * 256;
        o4.z = (yc1 * W_ + xc0) * 256;
        o4.w = (yc1 * W_ + xc1) * 256;
        spar_o[task] = o4;
    }
    // within-wave C'->D dependency: drain LDS writes, no block barrier needed
    __asm__ volatile("s_waitcnt lgkmcnt(0)" ::: "memory");

    // ---- persistent accumulators for main GEMM (2 row-halves) ----
    int m = lane & 15, q = lane >> 4;
    int o0 = wv * 16 + m;
    float b0v = bias[o0];
    f32x4 acc00 = {b0v, b0v, b0v, b0v};        // h=0, even K-slice
    f32x4 acc01 = {0.f, 0.f, 0.f, 0.f};        // h=0, odd
    f32x4 acc10 = {b0v, b0v, b0v, b0v};        // h=1, even
    f32x4 acc11 = {0.f, 0.f, 0.f, 0.f};        // h=1, odd
    const unsigned short* br0 = wB + o0 * KTOT + q * 8;
    const unsigned short* arow0 = sAc + m * CP32 + q * 8;
    const unsigned short* arow1 = sAc + (16 + m) * CP32 + q * 8;

    unsigned lane4 = (unsigned)lane << 2;
    const char* xu = (const char*)xt + (size_t)b * ((size_t)HW_ * 64 * 4);

    // ---- chunks: D_c gather (3 taps, 96 tasks) -> sAc ; E_c 12-MFMA ----
#pragma unroll
    for (int c = 0; c < 3; c++) {
        // D_c: this wave's 24 tasks, four 6-task batches (R10-proven pattern)
#pragma unroll
        for (int g = 0; g < 4; g++) {
            float v00[6], v01[6], v10[6], v11[6];
#pragma unroll
            for (int j = 0; j < 6; j++) {
                int task = 96 * c + (g * 6 + j) * 4 + wv;
                int4 o4 = spar_o[task];
                v00[j] = *(const float*)(xu + ((unsigned)o4.x + lane4));
                v01[j] = *(const float*)(xu + ((unsigned)o4.y + lane4));
                v10[j] = *(const float*)(xu + ((unsigned)o4.z + lane4));
                v11[j] = *(const float*)(xu + ((unsigned)o4.w + lane4));
            }
#pragma unroll
            for (int j = 0; j < 6; j++) {
                int task = 96 * c + (g * 6 + j) * 4 + wv;
                float4 w4 = spar_w[task];
                int p = task & 31, kc = (task >> 5) - 3 * c;   // local tap 0..2
                float v = v00[j] * w4.x + v01[j] * w4.y
                        + v10[j] * w4.z + v11[j] * w4.w;
                sAc[p * CP32 + kc * 64 + lane] = bfc(v);
            }
        }

        // preload E_c's B-fragments (NAMED regs; issued under gather latency,
        // carried across one barrier -- acc precedent, not the array trap)
        bf16x8 bb0 = *(const bf16x8*)(br0 + ((c * 3 + 0) * 2) * 32);
        bf16x8 bb1 = *(const bf16x8*)(br0 + ((c * 3 + 0) * 2 + 1) * 32);
        bf16x8 bb2 = *(const bf16x8*)(br0 + ((c * 3 + 1) * 2) * 32);
        bf16x8 bb3 = *(const bf16x8*)(br0 + ((c * 3 + 1) * 2 + 1) * 32);
        bf16x8 bb4 = *(const bf16x8*)(br0 + ((c * 3 + 2) * 2) * 32);
        bf16x8 bb5 = *(const bf16x8*)(br0 + ((c * 3 + 2) * 2 + 1) * 32);

        __syncthreads();

        // E_c: 3 local taps x 2 K-slices x 2 halves; B-frags preloaded
        {
            bf16x8 a00, a01, a10, a11;
            a00 = *(const bf16x8*)(arow0 + 0 * 32);
            a01 = *(const bf16x8*)(arow0 + 1 * 32);
            a10 = *(const bf16x8*)(arow1 + 0 * 32);
            a11 = *(const bf16x8*)(arow1 + 1 * 32);
            acc00 = __builtin_amdgcn_mfma_f32_16x16x32_bf16(a00, bb0, acc00, 0, 0, 0);
            acc01 = __builtin_amdgcn_mfma_f32_16x16x32_bf16(a01, bb1, acc01, 0, 0, 0);
            acc10 = __builtin_amdgcn_mfma_f32_16x16x32_bf16(a10, bb0, acc10, 0, 0, 0);
            acc11 = __builtin_amdgcn_mfma_f32_16x16x32_bf16(a11, bb1, acc11, 0, 0, 0);
            a00 = *(const bf16x8*)(arow0 + 2 * 32);
            a01 = *(const bf16x8*)(arow0 + 3 * 32);
            a10 = *(const bf16x8*)(arow1 + 2 * 32);
            a11 = *(const bf16x8*)(arow1 + 3 * 32);
            acc00 = __builtin_amdgcn_mfma_f32_16x16x32_bf16(a00, bb2, acc00, 0, 0, 0);
            acc01 = __builtin_amdgcn_mfma_f32_16x16x32_bf16(a01, bb3, acc01, 0, 0, 0);
            acc10 = __builtin_amdgcn_mfma_f32_16x16x32_bf16(a10, bb2, acc10, 0, 0, 0);
            acc11 = __builtin_amdgcn_mfma_f32_16x16x32_bf16(a11, bb3, acc11, 0, 0, 0);
            a00 = *(const bf16x8*)(arow0 + 4 * 32);
            a01 = *(const bf16x8*)(arow0 + 5 * 32);
            a10 = *(const bf16x8*)(arow1 + 4 * 32);
            a11 = *(const bf16x8*)(arow1 + 5 * 32);
            acc00 = __builtin_amdgcn_mfma_f32_16x16x32_bf16(a00, bb4, acc00, 0, 0, 0);
            acc01 = __builtin_amdgcn_mfma_f32_16x16x32_bf16(a01, bb5, acc01, 0, 0, 0);
            acc10 = __builtin_amdgcn_mfma_f32_16x16x32_bf16(a10, bb4, acc10, 0, 0, 0);
            acc11 = __builtin_amdgcn_mfma_f32_16x16x32_bf16(a11, bb5, acc11, 0, 0, 0);
        }
        if (c < 2) __syncthreads();    // E_c reads done before D_{c+1} overwrites
    }

#pragma unroll
    for (int r = 0; r < 4; r++) { acc00[r] += acc01[r]; acc10[r] += acc11[r]; }

    // ---- direct store: half 0 -> row ho, half 1 -> row ho+1 ----
    size_t a0 = ((size_t)(b * COUT + o0)) * HW_ + (size_t)ho * W_ + wo0 + q * 4;
    float4 r0; r0.x = acc00[0]; r0.y = acc00[1]; r0.z = acc00[2]; r0.w = acc00[3];
    *(float4*)(out + a0) = r0;
    float4 r1; r1.x = acc10[0]; r1.y = acc10[1]; r1.z = acc10[2]; r1.w = acc10[3];
    *(float4*)(out + a0 + W_) = r1;
}

// ---------------------------------------------------------------------------
extern "C" void kernel_launch(void* const* d_in, const int* in_sizes, int n_in,
                              void* d_out, int out_size, void* d_ws, size_t ws_size,
                              hipStream_t stream) {
    const float* x    = (const float*)d_in[0];   // (4,64,160,160)
    const float* ow   = (const float*)d_in[1];   // (27,64,3,3)
    const float* ob   = (const float*)d_in[2];   // (27,)
    const float* wgt  = (const float*)d_in[3];   // (64,64,3,3)
    const float* bias = (const float*)d_in[4];   // (64,)
    float* out = (float*)d_out;                  // (4,64,160,160) fp32

    // workspace: xt fp32 NHWC | wB bf16 | wB2 bf16   (~26.3 MB)
    float* ws  = (float*)d_ws;
    float* xt  = ws;                                            // 6,553,600 f32
    unsigned short* wB  = (unsigned short*)(xt + (size_t)B_ * HW_ * CIN);  // 36,864 u16
    unsigned short* wB2 = wB + (size_t)COUT * KTOT;                        // 18,432 u16

    prep_all_k<<<1816, 256, 0, stream>>>(x, wgt, ow, xt, wB, wB2);
    fused_dcn_k<<<NT32, 256, 0, stream>>>(xt, wB2, ob, wB, bias, out);
}

// Round 16
// 178.556 us; speedup vs baseline: 1.0658x; 1.0056x over previous
//
#include <hip/hip_runtime.h>
#include <hip/hip_bf16.h>
#include <math.h>

#define B_ 4
#define CIN 64
#define H_ 160
#define W_ 160
#define COUT 64
#define KK_ 9
#define HW_ (H_ * W_)
#define KTOT 576      // 9 taps * 64 channels
#define CP32 200      // sAc pitch (u16): 400 B, 100 dw == 4 mod 32 banks
#define XPITCH 72     // strip pitch (u16): 144 B, bank-rotating
#define SL32 33       // slog pitch (floats): 33 dw == 1 mod 32, rotating
#define NT32 3200     // (B*HW)/32
#define TPX32 400     // tiles per XCD slice (NT32/8)

typedef __attribute__((ext_vector_type(8))) short bf16x8;
typedef __attribute__((ext_vector_type(4))) float f32x4;

__device__ inline unsigned short f2bf(float f) {
    unsigned int u = __float_as_uint(f);
    u = (u + 0x7FFF + ((u >> 16) & 1)) >> 16;   // round-to-nearest-even
    return (unsigned short)u;
}

// HW bf16 convert (RNE, bit-identical to f2bf on finite inputs), 1 VALU op
__device__ inline unsigned short bfc(float f) {
    __hip_bfloat16 h = __float2bfloat16(f);
    union { __hip_bfloat16 h; unsigned short u; } cv;
    cv.h = h;
    return cv.u;
}

// ---------------------------------------------------------------------------
// Kernel 1 (merged prep): grid-split into
//   [0, 1600)        : transpose x (NCHW fp32) -> xt NHWC fp32 (float4 both sides)
//   [1600, 1744)     : main weight -> wB bf16 [o][tap*64+c]
//   [1744, 1816)     : offset weight -> wB2 bf16 [n(32,pad0)][tap*64+c]
// ---------------------------------------------------------------------------
__global__ __launch_bounds__(256) void prep_all_k(const float* __restrict__ x,
                                                  const float* __restrict__ wgt,
                                                  const float* __restrict__ ow,
                                                  float* __restrict__ xt,
                                                  unsigned short* __restrict__ wB,
                                                  unsigned short* __restrict__ wB2) {
    __shared__ float tile[64][65];
    int bid = blockIdx.x;
    int t = threadIdx.x;

    if (bid < 1600) {
        int pbk = bid % 400, b = bid / 400;    // 400 pixel-blocks of 64 per image
        int p0 = pbk * 64;
        const float* xp = x + (size_t)b * CIN * HW_ + p0;

        int pg = (t & 15) * 4, cr = t >> 4;
#pragma unroll
        for (int i = 0; i < 4; i++) {
            int c = i * 16 + cr;
            float4 v = *(const float4*)(xp + (size_t)c * HW_ + pg);
            tile[c][pg]     = v.x;
            tile[c][pg + 1] = v.y;
            tile[c][pg + 2] = v.z;
            tile[c][pg + 3] = v.w;
        }
        __syncthreads();

        int c4 = (t & 15) * 4, pr = t >> 4;
        float* op = xt + ((size_t)b * HW_ + p0) * 64 + c4;
#pragma unroll
        for (int i = 0; i < 4; i++) {
            int p = i * 16 + pr;
            float4 v;
            v.x = tile[c4][p];
            v.y = tile[c4 + 1][p];
            v.z = tile[c4 + 2][p];
            v.w = tile[c4 + 3][p];
            *(float4*)(op + (size_t)p * 64) = v;
        }
    } else if (bid < 1744) {
        int i = (bid - 1600) * 256 + t;          // 64*576 = 36864
        int o = i / KTOT, r = i % KTOT;
        int tap = r >> 6, c = r & 63;
        wB[i] = f2bf(wgt[(o * CIN + c) * KK_ + tap]);
    } else {
        int i = (bid - 1744) * 256 + t;          // 32*576 = 18432
        int n = i / KTOT, r = i % KTOT;
        int tap = r >> 6, c = r & 63;
        wB2[i] = (n < 27) ? f2bf(ow[(n * CIN + c) * KK_ + tap]) : (unsigned short)0;
    }
}

// ---------------------------------------------------------------------------
// Kernel 2: FUSED DCNv2, 2x16 tile, K-chunked.  (Session-best, verified R14:
//  total 179.6 us, fused ~101 us, clean counters.)
//  A : 4x18 halo strip (72 rows) -> sX bf16 (10.4 KB)
//  B : offset GEMM, all 4 waves; strip row = (h + tap/3)*18 + m + tap%3
//  C': bilinear params; spar_o = plain int4 full byte offsets (the only
//      addressing path that compiles clean on this compiler)
//  chunks c=0..2: D_c gather (24 tasks/wave, four 6-task batches) -> sAc;
//      E_c's wB B-frags preloaded in NAMED regs under the gather latency;
//      E_c 12 MFMA/wave, accumulate
//  Store: half h=0 -> row ho, h=1 -> row ho+1.
//  LDS 25.6 KB -> 6 blocks/CU cap (~4.4 resident = measured TLP knee).
//  Floor analysis (R14): ~10-11K cy/block serial chain, dominated by 12
//  L2-latency gather rounds; counted-vmcnt pipelining unreachable from HIP
//  source (4 attempts -> scratch spill / scheduler denial).
// ---------------------------------------------------------------------------
__global__ __launch_bounds__(256, 6) void fused_dcn_k(const float* __restrict__ xt,
                                                      const unsigned short* __restrict__ wB2,
                                                      const float* __restrict__ ob,
                                                      const unsigned short* __restrict__ wB,
                                                      const float* __restrict__ bias,
                                                      float* __restrict__ out) {
    __shared__ __align__(16) char ubuf[12800];             // sX (A/B) -> sAc (D/E)
    __shared__ __align__(16) char pbuf[288 * 32];          // spar_w | spar_o, 9.2 KB
    __shared__ float slog[27 * SL32];                      // 3.6 KB
    unsigned short* sX  = (unsigned short*)ubuf;           // 72 x XPITCH (10.4 KB)
    unsigned short* sAc = (unsigned short*)ubuf;           // 32 x CP32 (12.8 KB)
    float4* spar_w = (float4*)pbuf;
    int4*   spar_o = (int4*)(pbuf + 288 * 16);

    int t = threadIdx.x;
    int lane = t & 63, wv = t >> 6;
    int bid = blockIdx.x;
    int t2 = (bid & 7) * TPX32 + (bid >> 3);   // XCD-contiguous tile index
    int b  = t2 / 800;                         // 800 2x16-tiles per image
    int ti = t2 % 800;                         // 80 row-pairs x 10 col-segs
    int ho  = (ti / 10) * 2;
    int wo0 = (ti % 10) * 16;

    const float* xb = xt + (size_t)b * HW_ * 64 + lane;

    // ---- phase A: 72-row halo strip (4 rows x 18 cols), lanes = channels ----
#pragma unroll
    for (int i = 0; i < 18; i++) {
        int r = i * 4 + wv;             // 0..71
        int ry = r / 18, rx = r % 18;
        int yy = ho - 1 + ry;
        int xx = wo0 - 1 + rx;
        float v = 0.f;
        if (yy >= 0 && yy < H_ && xx >= 0 && xx < W_)
            v = xb[(size_t)(yy * W_ + xx) * 64];
        sX[r * XPITCH + lane] = bfc(v);
    }
    __syncthreads();

    // ---- phase B: offset GEMM, all 4 waves (h = wv>>1, oc-tile wv&1) ----
    {
        int m = lane & 15, q = lane >> 4;
        int h  = wv >> 1;
        int ocl = (wv & 1) * 16 + m;
        float bv = (ocl < 27) ? ob[ocl] : 0.f;
        f32x4 acc  = {bv, bv, bv, bv};
        f32x4 acc2 = {0.f, 0.f, 0.f, 0.f};
        const unsigned short* brow = wB2 + ocl * KTOT + q * 8;
#pragma unroll
        for (int tap = 0; tap < 9; tap++) {
            int row = (h + tap / 3) * 18 + m + (tap % 3);   // strip row
            const unsigned short* sxr = sX + row * XPITCH + q * 8;
            bf16x8 af0 = *(const bf16x8*)(sxr);
            bf16x8 af1 = *(const bf16x8*)(sxr + 32);
            bf16x8 b0  = *(const bf16x8*)(brow + (2 * tap) * 32);
            bf16x8 b1  = *(const bf16x8*)(brow + (2 * tap + 1) * 32);
            acc  = __builtin_amdgcn_mfma_f32_16x16x32_bf16(af0, b0, acc,  0, 0, 0);
            acc2 = __builtin_amdgcn_mfma_f32_16x16x32_bf16(af1, b1, acc2, 0, 0, 0);
        }
#pragma unroll
        for (int r = 0; r < 4; r++) acc[r] += acc2[r];
        if (ocl < 27) {
            float* sl = slog + ocl * SL32 + h * 16 + q * 4;     // pixel p32
            if (ocl < 18) {
#pragma unroll
                for (int r = 0; r < 4; r++) sl[r] = acc[r];
            } else {
#pragma unroll
                for (int r = 0; r < 4; r++) sl[r] = 1.f / (1.f + expf(-acc[r]));
            }
        }
    }
    __syncthreads();

    // ---- phase C': bilinear params, per-wave task subset {l*4+wv} ----
    for (int l = lane; l < 72; l += 64) {
        int task = l * 4 + wv;                 // < 288
        int p = task & 31, k = task >> 5;
        int h = p >> 4, col = p & 15;
        float dyv = slog[(2 * k) * SL32 + p];
        float dxv = slog[(2 * k + 1) * SL32 + p];
        float mv  = slog[(18 + k) * SL32 + p];
        float py = dyv + (float)(k / 3) + (float)(ho + h - 1);
        float px = dxv + (float)(k % 3) + (float)(wo0 + col - 1);
        float y0f = floorf(py), x0f = floorf(px);
        float wy1 = py - y0f, wx1 = px - x0f;
        float wy0 = 1.f - wy1, wx0 = 1.f - wx1;
        int y0 = (int)y0f, x0 = (int)x0f;
        bool yv0 = (y0 >= 0) && (y0 < H_);
        bool yv1 = (y0 + 1 >= 0) && (y0 + 1 < H_);
        bool xv0 = (x0 >= 0) && (x0 < W_);
        bool xv1 = (x0 + 1 >= 0) && (x0 + 1 < W_);
        float4 w4;
        w4.x = (yv0 && xv0) ? wy0 * wx0 * mv : 0.f;
        w4.y = (yv0 && xv1) ? wy0 * wx1 * mv : 0.f;
        w4.z = (yv1 && xv0) ? wy1 * wx0 * mv : 0.f;
        w4.w = (yv1 && xv1) ? wy1 * wx1 * mv : 0.f;
        spar_w[task] = w4;
        int yc0 = min(max(y0, 0), H_ - 1), yc1 = min(max(y0 + 1, 0), H_ - 1);
        int xc0 = min(max(x0, 0), W_ - 1), xc1 = min(max(x0 + 1, 0), W_ - 1);
        int4 o4;                               // BYTE offsets (elem*64*4)
        o4.x = (yc0 * W_ + xc0) * 256;
        o4.y = (yc0 * W_ + xc1) * 256;
        o4.z = (yc1 * W_ + xc0) * 256;
        o4.w = (yc1 * W_ + xc1) * 256;
        spar_o[task] = o4;
    }
    // within-wave C'->D dependency: drain LDS writes, no block barrier needed
    __asm__ volatile("s_waitcnt lgkmcnt(0)" ::: "memory");

    // ---- persistent accumulators for main GEMM (2 row-halves) ----
    int m = lane & 15, q = lane >> 4;
    int o0 = wv * 16 + m;
    float b0v = bias[o0];
    f32x4 acc00 = {b0v, b0v, b0v, b0v};        // h=0, even K-slice
    f32x4 acc01 = {0.f, 0.f, 0.f, 0.f};        // h=0, odd
    f32x4 acc10 = {b0v, b0v, b0v, b0v};        // h=1, even
    f32x4 acc11 = {0.f, 0.f, 0.f, 0.f};        // h=1, odd
    const unsigned short* br0 = wB + o0 * KTOT + q * 8;
    const unsigned short* arow0 = sAc + m * CP32 + q * 8;
    const unsigned short* arow1 = sAc + (16 + m) * CP32 + q * 8;

    unsigned lane4 = (unsigned)lane << 2;
    const char* xu = (const char*)xt + (size_t)b * ((size_t)HW_ * 64 * 4);

    // ---- chunks: D_c gather (3 taps, 96 tasks) -> sAc ; E_c 12-MFMA ----
#pragma unroll
    for (int c = 0; c < 3; c++) {
        // D_c: this wave's 24 tasks, four 6-task batches (R10-proven pattern)
#pragma unroll
        for (int g = 0; g < 4; g++) {
            float v00[6], v01[6], v10[6], v11[6];
#pragma unroll
            for (int j = 0; j < 6; j++) {
                int task = 96 * c + (g * 6 + j) * 4 + wv;
                int4 o4 = spar_o[task];
                v00[j] = *(const float*)(xu + ((unsigned)o4.x + lane4));
                v01[j] = *(const float*)(xu + ((unsigned)o4.y + lane4));
                v10[j] = *(const float*)(xu + ((unsigned)o4.z + lane4));
                v11[j] = *(const float*)(xu + ((unsigned)o4.w + lane4));
            }
#pragma unroll
            for (int j = 0; j < 6; j++) {
                int task = 96 * c + (g * 6 + j) * 4 + wv;
                float4 w4 = spar_w[task];
                int p = task & 31, kc = (task >> 5) - 3 * c;   // local tap 0..2
                float v = v00[j] * w4.x + v01[j] * w4.y
                        + v10[j] * w4.z + v11[j] * w4.w;
                sAc[p * CP32 + kc * 64 + lane] = bfc(v);
            }
        }

        // preload E_c's B-fragments (NAMED regs; issued under gather latency,
        // carried across one barrier -- acc precedent, not the array trap)
        bf16x8 bb0 = *(const bf16x8*)(br0 + ((c * 3 + 0) * 2) * 32);
        bf16x8 bb1 = *(const bf16x8*)(br0 + ((c * 3 + 0) * 2 + 1) * 32);
        bf16x8 bb2 = *(const bf16x8*)(br0 + ((c * 3 + 1) * 2) * 32);
        bf16x8 bb3 = *(const bf16x8*)(br0 + ((c * 3 + 1) * 2 + 1) * 32);
        bf16x8 bb4 = *(const bf16x8*)(br0 + ((c * 3 + 2) * 2) * 32);
        bf16x8 bb5 = *(const bf16x8*)(br0 + ((c * 3 + 2) * 2 + 1) * 32);

        __syncthreads();

        // E_c: 3 local taps x 2 K-slices x 2 halves; B-frags preloaded
        {
            bf16x8 a00, a01, a10, a11;
            a00 = *(const bf16x8*)(arow0 + 0 * 32);
            a01 = *(const bf16x8*)(arow0 + 1 * 32);
            a10 = *(const bf16x8*)(arow1 + 0 * 32);
            a11 = *(const bf16x8*)(arow1 + 1 * 32);
            acc00 = __builtin_amdgcn_mfma_f32_16x16x32_bf16(a00, bb0, acc00, 0, 0, 0);
            acc01 = __builtin_amdgcn_mfma_f32_16x16x32_bf16(a01, bb1, acc01, 0, 0, 0);
            acc10 = __builtin_amdgcn_mfma_f32_16x16x32_bf16(a10, bb0, acc10, 0, 0, 0);
            acc11 = __builtin_amdgcn_mfma_f32_16x16x32_bf16(a11, bb1, acc11, 0, 0, 0);
            a00 = *(const bf16x8*)(arow0 + 2 * 32);
            a01 = *(const bf16x8*)(arow0 + 3 * 32);
            a10 = *(const bf16x8*)(arow1 + 2 * 32);
            a11 = *(const bf16x8*)(arow1 + 3 * 32);
            acc00 = __builtin_amdgcn_mfma_f32_16x16x32_bf16(a00, bb2, acc00, 0, 0, 0);
            acc01 = __builtin_amdgcn_mfma_f32_16x16x32_bf16(a01, bb3, acc01, 0, 0, 0);
            acc10 = __builtin_amdgcn_mfma_f32_16x16x32_bf16(a10, bb2, acc10, 0, 0, 0);
            acc11 = __builtin_amdgcn_mfma_f32_16x16x32_bf16(a11, bb3, acc11, 0, 0, 0);
            a00 = *(const bf16x8*)(arow0 + 4 * 32);
            a01 = *(const bf16x8*)(arow0 + 5 * 32);
            a10 = *(const bf16x8*)(arow1 + 4 * 32);
            a11 = *(const bf16x8*)(arow1 + 5 * 32);
            acc00 = __builtin_amdgcn_mfma_f32_16x16x32_bf16(a00, bb4, acc00, 0, 0, 0);
            acc01 = __builtin_amdgcn_mfma_f32_16x16x32_bf16(a01, bb5, acc01, 0, 0, 0);
            acc10 = __builtin_amdgcn_mfma_f32_16x16x32_bf16(a10, bb4, acc10, 0, 0, 0);
            acc11 = __builtin_amdgcn_mfma_f32_16x16x32_bf16(a11, bb5, acc11, 0, 0, 0);
        }
        if (c < 2) __syncthreads();    // E_c reads done before D_{c+1} overwrites
    }

#pragma unroll
    for (int r = 0; r < 4; r++) { acc00[r] += acc01[r]; acc10[r] += acc11[r]; }

    // ---- direct store: half 0 -> row ho, half 1 -> row ho+1 ----
    size_t a0 = ((size_t)(b * COUT + o0)) * HW_ + (size_t)ho * W_ + wo0 + q * 4;
    float4 r0; r0.x = acc00[0]; r0.y = acc00[1]; r0.z = acc00[2]; r0.w = acc00[3];
    *(float4*)(out + a0) = r0;
    float4 r1; r1.x = acc10[0]; r1.y = acc10[1]; r1.z = acc10[2]; r1.w = acc10[3];
    *(float4*)(out + a0 + W_) = r1;
}

// ---------------------------------------------------------------------------
extern "C" void kernel_launch(void* const* d_in, const int* in_sizes, int n_in,
                              void* d_out, int out_size, void* d_ws, size_t ws_size,
                              hipStream_t stream) {
    const float* x    = (const float*)d_in[0];   // (4,64,160,160)
    const float* ow   = (const float*)d_in[1];   // (27,64,3,3)
    const float* ob   = (const float*)d_in[2];   // (27,)
    const float* wgt  = (const float*)d_in[3];   // (64,64,3,3)
    const float* bias = (const float*)d_in[4];   // (64,)
    float* out = (float*)d_out;                  // (4,64,160,160) fp32

    // workspace: xt fp32 NHWC | wB bf16 | wB2 bf16   (~26.3 MB)
    float* ws  = (float*)d_ws;
    float* xt  = ws;                                            // 6,553,600 f32
    unsigned short* wB  = (unsigned short*)(xt + (size_t)B_ * HW_ * CIN);  // 36,864 u16
    unsigned short* wB2 = wB + (size_t)COUT * KTOT;                        // 18,432 u16

    prep_all_k<<<1816, 256, 0, stream>>>(x, wgt, ow, xt, wB, wB2);
    fused_dcn_k<<<NT32, 256, 0, stream>>>(xt, wB2, ob, wB, bias, out);
}